// Round 10
// baseline (409.608 us; speedup 1.0000x reference)
//
#include <hip/hip_runtime.h>

#define TT 200
#define BB 256
#define DD 128
#define HH 128
#define NG 896  // 7*H, gate-major semantic layout

typedef _Float16 half8 __attribute__((ext_vector_type(8)));
typedef _Float16 half4 __attribute__((ext_vector_type(4)));
typedef float float4v __attribute__((ext_vector_type(4)));

__device__ __forceinline__ float rcpf_(float x) { return __builtin_amdgcn_rcpf(x); }
__device__ __forceinline__ float sigmoidf_(float x) { return rcpf_(1.f + __expf(-x)); }
__device__ __forceinline__ float tanhf_(float x) { return 1.f - 2.f * rcpf_(__expf(2.f * x) + 1.f); }
__device__ __forceinline__ float softplusf_(float x) {
  return fmaxf(x, 0.f) + 0.69314718056f * __log2f(1.f + __expf(-fabsf(x)));
}

// Transpose + f16-cast: W[k][j] (k<128, j<896 semantic g*128+u) -> WT[j][k]
__global__ __launch_bounds__(256) void wtrans_k(const float* __restrict__ Wx,
    const float* __restrict__ Wh, _Float16* __restrict__ WxT, _Float16* __restrict__ WhT) {
  int idx = blockIdx.x * 256 + threadIdx.x;
  if (idx < DD * NG) {
    int k = idx / NG, jj = idx % NG;
    WxT[jj * DD + k] = (_Float16)Wx[idx];
  } else if (idx < 2 * DD * NG) {
    int i2 = idx - DD * NG;
    int k = i2 / NG, jj = i2 % NG;
    WhT[jj * DD + k] = (_Float16)Wh[i2];
  }
}

// xg GEMM writing C-FRAGMENT-ORDER output:
// xgA[(((t_rel*16 + grp)*7 + g)*8 + utile)*256 + lane*4 + r]
//   = x[b = grp*16 + (lane>>4)*4 + r, t, :] @ W_x[:, g*128 + utile*16 + (lane&15)] + bias
// This is exactly the 16x16x32 C layout, so rec_k loads one half4 per gate.
__global__ __launch_bounds__(256, 2) void xg_gemm_k(const float* __restrict__ x,
    const _Float16* __restrict__ WxT, const float* __restrict__ bias,
    _Float16* __restrict__ xgA, int t0) {
  int mt = blockIdx.x;
  __shared__ _Float16 Ald[128][136];
  __shared__ _Float16 Bld[128][136];
  int tid = threadIdx.x;
  int G0 = mt * 128;
  int t = t0 + (G0 >> 8);
  int b0 = G0 & 255;
  {  // coalesced f32 load of x[b0..b0+128)[t][0..128) -> f16 in Ald
    int r = tid >> 5, kq = (tid & 31) << 2;
#pragma unroll
    for (int it = 0; it < 16; ++it) {
      int row = r + it * 8;
      float4v xv = *(const float4v*)(x + ((size_t)(b0 + row) * TT + t) * DD + kq);
      half4 h4 = {(_Float16)xv[0], (_Float16)xv[1], (_Float16)xv[2], (_Float16)xv[3]};
      *(half4*)&Ald[row][kq] = h4;
    }
  }
  __syncthreads();
  int wv = tid >> 6, l = tid & 63, lr = l & 15, lk8 = (l >> 4) << 3;
  half8 af[2][4];
#pragma unroll
  for (int mf = 0; mf < 2; ++mf)
#pragma unroll
    for (int kk = 0; kk < 4; ++kk)
      af[mf][kk] = *(const half8*)&Ald[wv * 32 + mf * 16 + lr][kk * 32 + lk8];

  size_t trel16 = (size_t)(t - t0) * 16;
  for (int nt = 0; nt < 7; ++nt) {  // nt = gate
    for (int i = tid; i < 128 * 16; i += 256) {
      int r = i >> 4, c8 = (i & 15) << 3;
      *(half8*)&Bld[r][c8] = *(const half8*)(WxT + (size_t)(nt * 128 + r) * DD + c8);
    }
    __syncthreads();
    float4v acc[2][8];
#pragma unroll
    for (int a = 0; a < 2; ++a)
#pragma unroll
      for (int q = 0; q < 8; ++q) acc[a][q] = (float4v){0.f, 0.f, 0.f, 0.f};
#pragma unroll
    for (int kk = 0; kk < 4; ++kk) {
#pragma unroll
      for (int nf = 0; nf < 8; ++nf) {
        half8 bv = *(const half8*)&Bld[nf * 16 + lr][kk * 32 + lk8];
        acc[0][nf] = __builtin_amdgcn_mfma_f32_16x16x32_f16(af[0][kk], bv, acc[0][nf], 0, 0, 0);
        acc[1][nf] = __builtin_amdgcn_mfma_f32_16x16x32_f16(af[1][kk], bv, acc[1][nf], 0, 0, 0);
      }
    }
#pragma unroll
    for (int nf = 0; nf < 8; ++nf) {
      int col = nt * 128 + nf * 16 + lr;
      float bv = bias[col];
#pragma unroll
      for (int mf = 0; mf < 2; ++mf) {
        int grp = (b0 >> 4) + wv * 2 + mf;
        half4 h4;
#pragma unroll
        for (int rr = 0; rr < 4; ++rr) h4[rr] = (_Float16)(acc[mf][nf][rr] + bv);
        *(half4*)&xgA[(((trel16 + grp) * 7 + nt) * 8 + nf) * 256 + l * 4] = h4;
      }
    }
    __syncthreads();
  }
}

// Sample-batched MFMA recurrence: 16 blocks, each owns 16 samples.
// 512 threads (8 waves). Wave w = unit-tile (units w*16..w*16+16). A-fragment
// rows = 16 samples' h (from LDS H). Per wave: 7 gate-tiles x 4 chained MFMAs.
// C layout: lane (lr,lg) holds, for gate g, rows lg*4+r (= samples) at col lr
// (= unit w*16+lr) -> each lane updates 4 (sample,unit) pairs with ALL gates
// local, no replication. h exchange: 4 ds_write_b16 + one barrier per step.
__global__ __launch_bounds__(512, 2) void rec_k(const _Float16* __restrict__ xgA,
    const float* __restrict__ dur, const int* __restrict__ rep,
    const _Float16* __restrict__ WhT, float* __restrict__ out,
    _Float16* __restrict__ st_h, float* __restrict__ st_c, float* __restrict__ st_cb,
    int t0, int t1) {
  int grp = blockIdx.x, j = threadIdx.x;
  int tmax = 0;
#pragma unroll
  for (int s = 0; s < 16; ++s) tmax = max(tmax, rep[grp * 16 + s]);  // uniform
  if (t0 > tmax) return;  // block-uniform
  int tstop = min(t1 - 1, tmax);

  __shared__ int tends[16];
  __shared__ float dl[16][TT];
  __shared__ __align__(16) _Float16 H[2][16][136];  // padded rows
  int w = j >> 6, l = j & 63, lr = l & 15, lg = l >> 4;
  int u = w * 16 + lr;

  if (j < 16) tends[j] = rep[grp * 16 + j];
  for (int idx = j; idx < 16 * TT; idx += 512) {
    int s = idx / TT, tt2 = idx - s * TT;
    dl[s][tt2] = dur[(grp * 16 + s) * TT + tt2];
  }
  // resident W_h fragments: wb[g][kk] (112 VGPR)
  half8 wb[7][4];
#pragma unroll
  for (int g = 0; g < 7; ++g)
#pragma unroll
    for (int kk = 0; kk < 4; ++kk)
      wb[g][kk] = *(const half8*)(WhT + (size_t)(g * HH + u) * DD + kk * 32 + lg * 8);
  for (int idx = j; idx < 16 * 128; idx += 512) {
    int s = idx >> 7, uu = idx & 127;
    H[0][s][uu] = (t0 == 0) ? (_Float16)0.f : st_h[(grp * 16 + s) * HH + uu];
    H[1][s][uu] = (_Float16)0.f;
  }
  float c_s[4], cb_s[4], hs[4];
#pragma unroll
  for (int r = 0; r < 4; ++r) {
    int s = lg * 4 + r;
    c_s[r] = (t0 == 0) ? 0.f : st_c[(grp * 16 + s) * HH + u];
    cb_s[r] = (t0 == 0) ? 0.f : st_cb[(grp * 16 + s) * HH + u];
    hs[r] = 0.f;
  }
  __syncthreads();
  int te[4];
#pragma unroll
  for (int r = 0; r < 4; ++r) te[r] = tends[lg * 4 + r];

  const size_t stp = (size_t)16 * 7 * 8 * 256;  // halfs per t
  const _Float16* xbase = xgA + ((size_t)grp * 7 * 8 + w) * 256 + l * 4;
  half4 cur[7], nxt[7];
#pragma unroll
  for (int g = 0; g < 7; ++g)
    cur[g] = *(const half4*)(xbase + (size_t)g * 8 * 256);

#define STEP(T, PIN, POUT)                                                       \
  do {                                                                           \
    half8 af[4];                                                                 \
    _Pragma("unroll") for (int kk = 0; kk < 4; ++kk)                             \
        af[kk] = *(const half8*)&H[PIN][lr][kk * 32 + lg * 8];                   \
    float4v acc[7];                                                              \
    _Pragma("unroll") for (int g = 0; g < 7; ++g) {                              \
      acc[g] = (float4v){(float)cur[g][0], (float)cur[g][1], (float)cur[g][2],   \
                         (float)cur[g][3]};                                      \
    }                                                                            \
    _Pragma("unroll") for (int kk = 0; kk < 4; ++kk)                             \
        _Pragma("unroll") for (int g = 0; g < 7; ++g)                            \
            acc[g] = __builtin_amdgcn_mfma_f32_16x16x32_f16(af[kk], wb[g][kk],   \
                                                            acc[g], 0, 0, 0);    \
    _Pragma("unroll") for (int r = 0; r < 4; ++r) {                              \
      int s = lg * 4 + r;                                                        \
      float dt = dl[s][T];                                                       \
      float iv = sigmoidf_(acc[0][r]), fv = sigmoidf_(acc[1][r]);                \
      float zv = tanhf_(acc[2][r]), ov = sigmoidf_(acc[3][r]);                   \
      float ibv = sigmoidf_(acc[4][r]), fbv = sigmoidf_(acc[5][r]);              \
      float dv = softplusf_(acc[6][r]);                                          \
      float cc = fv * c_s[r] + iv * zv;                                          \
      cb_s[r] = fbv * cb_s[r] + ibv * zv;                                        \
      float cn = cb_s[r] + (cc - cb_s[r]) * __expf(-dv * dt);                    \
      float hn = ov * tanhf_(cn);                                                \
      c_s[r] = cn;                                                               \
      hs[r] = hn;                                                                \
      if ((T) == te[r]) {                                                        \
        out[(grp * 16 + s) * HH + u] = hn;                                       \
        out[BB * HH + (grp * 16 + s) * HH + u] = cn;                             \
      }                                                                          \
      H[POUT][s][u] = (_Float16)hn;                                              \
    }                                                                            \
    __syncthreads();                                                             \
  } while (0)

  for (int tb = t0; tb <= tstop; tb += 2) {
#pragma unroll
    for (int g = 0; g < 7; ++g) {  // prefetch 2 steps ahead (clamped)
      nxt[g] = *(const half4*)(xbase + (size_t)(min(tb + 2, tstop) - t0) * stp +
                               (size_t)g * 8 * 256);
    }
    STEP(tb, 0, 1);
    if (tb + 1 <= tstop) {
#pragma unroll
      for (int g = 0; g < 7; ++g)
        cur[g] = *(const half4*)(xbase + (size_t)(tb + 1 - t0) * stp + (size_t)g * 8 * 256);
      STEP(tb + 1, 1, 0);
    }
#pragma unroll
    for (int g = 0; g < 7; ++g) cur[g] = nxt[g];
  }
#undef STEP

#pragma unroll
  for (int r = 0; r < 4; ++r) {  // save state for next chunk
    int s = lg * 4 + r;
    if (tstop < te[r]) {
      st_h[(grp * 16 + s) * HH + u] = (_Float16)hs[r];
      st_c[(grp * 16 + s) * HH + u] = c_s[r];
      st_cb[(grp * 16 + s) * HH + u] = cb_s[r];
    }
  }
}

extern "C" void kernel_launch(void* const* d_in, const int* in_sizes, int n_in,
                              void* d_out, int out_size, void* d_ws, size_t ws_size,
                              hipStream_t stream) {
  const float* x = (const float*)d_in[0];
  const float* dur = (const float*)d_in[1];
  const int* rep = (const int*)d_in[2];
  const float* Wx = (const float*)d_in[3];
  const float* Wh = (const float*)d_in[4];
  const float* bias = (const float*)d_in[5];
  float* out = (float*)d_out;
  char* ws = (char*)d_ws;

  size_t off = 0;
  _Float16* WxT = (_Float16*)(ws + off); off += (size_t)NG * DD * 2;
  _Float16* WhT = (_Float16*)(ws + off); off += (size_t)NG * DD * 2;
  _Float16* st_h = (_Float16*)(ws + off); off += (size_t)BB * HH * 2;
  float* st_c = (float*)(ws + off); off += (size_t)BB * HH * 4;
  float* st_cb = (float*)(ws + off); off += (size_t)BB * HH * 4;
  _Float16* xgA = (_Float16*)(ws + off);

  size_t avail = ws_size > off ? ws_size - off : 0;
  size_t perT = (size_t)BB * NG * 2;
  int Tc = (int)(avail / perT);
  if (Tc > TT) Tc = TT;
  if (Tc < 1) Tc = 1;

  hipLaunchKernelGGL(wtrans_k, dim3((2 * DD * NG + 255) / 256), dim3(256), 0, stream,
                     Wx, Wh, WxT, WhT);
  for (int t0 = 0; t0 < TT; t0 += Tc) {
    int t1 = t0 + Tc;
    if (t1 > TT) t1 = TT;
    int mtiles = (t1 - t0) * BB / 128;
    hipLaunchKernelGGL(xg_gemm_k, dim3(mtiles), dim3(256), 0, stream,
                       x, WxT, bias, xgA, t0);
    hipLaunchKernelGGL(rec_k, dim3(16), dim3(512), 0, stream,
                       xgA, dur, rep, WhT, out, st_h, st_c, st_cb, t0, t1);
  }
}

// Round 11
// 264.288 us; speedup vs baseline: 1.5499x; 1.5499x over previous
//
#include <hip/hip_runtime.h>

#define TT 200
#define BB 256
#define DD 128
#define HH 128
#define NG 896  // 7*H, gate-major semantic layout
#define CH 64   // timesteps of xg staged in LDS per chunk

typedef _Float16 half8 __attribute__((ext_vector_type(8)));
typedef float float4v __attribute__((ext_vector_type(4)));

__device__ __forceinline__ float rcpf_(float x) { return __builtin_amdgcn_rcpf(x); }
__device__ __forceinline__ float sigmoidf_(float x) { return rcpf_(1.f + __expf(-x)); }
__device__ __forceinline__ float tanhf_(float x) { return 1.f - 2.f * rcpf_(__expf(2.f * x) + 1.f); }
// softplus(x) = max(x,0) + ln(1+exp(-|x|))
__device__ __forceinline__ float softplusf_(float x) {
  return fmaxf(x, 0.f) + 0.69314718056f * __log2f(1.f + __expf(-fabsf(x)));
}

// Transpose + f16-cast: W[k][j] (k<128, j<896 semantic g*128+u) -> WT[j][k]
__global__ __launch_bounds__(256) void wtrans_k(const float* __restrict__ Wx,
    const float* __restrict__ Wh, _Float16* __restrict__ WxT, _Float16* __restrict__ WhT) {
  int idx = blockIdx.x * 256 + threadIdx.x;
  if (idx < DD * NG) {
    int k = idx / NG, jj = idx % NG;
    WxT[jj * DD + k] = (_Float16)Wx[idx];
  } else if (idx < 2 * DD * NG) {
    int i2 = idx - DD * NG;
    int k = i2 / NG, jj = i2 % NG;
    WhT[jj * DD + k] = (_Float16)Wh[i2];
  }
}

// Fused CT-LSTM: one block per sample, 512 threads (8 waves), single dispatch.
// Every CH=64 steps, the block computes its own xg chunk (x[b]@W_x + bias) with
// MFMA into LDS (xgL[t%64][u*8+g]), then runs the proven r5 recurrence STEP
// reading xg from LDS. Wave w, lane l: lr=l&15, lg=l>>4, unit u=w*16+lr.
// A = h broadcast to all 16 rows => acc[tt][0] = gate-tt preactivation for unit
// u (replicated over rows/lg); each lane does the full state update for u.
__global__ __launch_bounds__(512, 2) void rec_k(const float* __restrict__ x,
    const float* __restrict__ dur, const int* __restrict__ rep,
    const _Float16* __restrict__ WxT, const _Float16* __restrict__ WhT,
    const float* __restrict__ bias, float* __restrict__ out) {
  int b = blockIdx.x, j = threadIdx.x;
  int tend = rep[b];
  __shared__ __align__(16) _Float16 xgL[CH][1024];  // [t%CH][u*8+g], 131072 B
  __shared__ __align__(16) _Float16 hbuf[2][HH];
  __shared__ float dlds[TT];
  int w = j >> 6, l = j & 63, lr = l & 15, lg = l >> 4;
  int u = w * 16 + lr;

  // Resident W_h B-fragments: wb[g][kk] = WhT[col=g*128+u][k=kk*32+lg*8..+8]
  half8 wb[7][4];
#pragma unroll
  for (int g = 0; g < 7; ++g)
#pragma unroll
    for (int kk = 0; kk < 4; ++kk)
      wb[g][kk] = *(const half8*)(WhT + (size_t)(g * HH + u) * DD + kk * 32 + lg * 8);
  float bias_r[7];
#pragma unroll
  for (int g = 0; g < 7; ++g) bias_r[g] = bias[g * HH + u];
  for (int i = j; i < TT; i += 512) dlds[i] = dur[b * TT + i];
  if (lg == 0) {
    hbuf[0][u] = (_Float16)0.f;
    hbuf[1][u] = (_Float16)0.f;
  }
  float c_s = 0.f, cb_s = 0.f;
  __syncthreads();

#define STEP(T, CUR, PIN, POUT)                                                  \
  do {                                                                           \
    float dt = dlds[T];                                                          \
    half8 af[4];                                                                 \
    _Pragma("unroll") for (int kk = 0; kk < 4; ++kk)                             \
        af[kk] = *(const half8*)((const char*)hbuf[PIN] + kk * 64 + lg * 16);    \
    float4v acc[7];                                                              \
    _Pragma("unroll") for (int tt = 0; tt < 7; ++tt) {                           \
      float xv = (float)CUR[tt];                                                 \
      acc[tt] = (float4v){xv, xv, xv, xv};                                       \
    }                                                                            \
    _Pragma("unroll") for (int kk = 0; kk < 4; ++kk)                             \
        _Pragma("unroll") for (int tt = 0; tt < 7; ++tt)                         \
            acc[tt] = __builtin_amdgcn_mfma_f32_16x16x32_f16(af[kk], wb[tt][kk], \
                                                             acc[tt], 0, 0, 0);  \
    float iv = sigmoidf_(acc[0][0]), fv = sigmoidf_(acc[1][0]);                  \
    float zv = tanhf_(acc[2][0]), ov = sigmoidf_(acc[3][0]);                     \
    float ibv = sigmoidf_(acc[4][0]), fbv = sigmoidf_(acc[5][0]);                \
    float dv = softplusf_(acc[6][0]);                                            \
    float cc = fv * c_s + iv * zv;                                               \
    cb_s = fbv * cb_s + ibv * zv;                                                \
    float cn = cb_s + (cc - cb_s) * __expf(-dv * dt);                            \
    float hn = ov * tanhf_(cn);                                                  \
    c_s = cn;                                                                    \
    if (lg == 0) {                                                               \
      if ((T) == tend) {                                                         \
        out[b * HH + u] = hn;                                                    \
        out[BB * HH + b * HH + u] = cn;                                          \
      }                                                                          \
      hbuf[POUT][u] = (_Float16)hn;                                              \
    }                                                                            \
    __syncthreads();                                                             \
  } while (0)

  for (int tc = 0; tc <= tend; tc += CH) {
    // ---- GEMM phase: xgL[tr][u*8+g] = x[b,tc+tr,:]@W_x[:,g*128+u] + bias ----
    // (previous chunk's final STEP barrier guarantees xgL is no longer read)
    int tstop = min(tc + CH - 1, tend);
    int nrows = tstop - tc + 1;
    for (int m = 0; m < 4; ++m) {
      if (m * 16 >= nrows) break;  // block-uniform
      int t_r = min(tc + m * 16 + lr, TT - 1);  // clamp tail rows (never read)
      half8 axf[4];
#pragma unroll
      for (int kk = 0; kk < 4; ++kk) {
        const float* xp = x + ((size_t)b * TT + t_r) * DD + kk * 32 + lg * 8;
        float4v x0 = *(const float4v*)xp;
        float4v x1 = *(const float4v*)(xp + 4);
        half8 a;
        a[0] = (_Float16)x0[0]; a[1] = (_Float16)x0[1];
        a[2] = (_Float16)x0[2]; a[3] = (_Float16)x0[3];
        a[4] = (_Float16)x1[0]; a[5] = (_Float16)x1[1];
        a[6] = (_Float16)x1[2]; a[7] = (_Float16)x1[3];
        axf[kk] = a;
      }
#pragma unroll
      for (int g = 0; g < 7; ++g) {
        half8 bf[4];
#pragma unroll
        for (int kk = 0; kk < 4; ++kk)
          bf[kk] = *(const half8*)(WxT + (size_t)(g * HH + u) * DD + kk * 32 + lg * 8);
        float bv = bias_r[g];
        float4v acc = (float4v){bv, bv, bv, bv};
#pragma unroll
        for (int kk = 0; kk < 4; ++kk)
          acc = __builtin_amdgcn_mfma_f32_16x16x32_f16(axf[kk], bf[kk], acc, 0, 0, 0);
#pragma unroll
        for (int r = 0; r < 4; ++r)
          xgL[m * 16 + lg * 4 + r][u * 8 + g] = (_Float16)acc[r];
      }
    }
    __syncthreads();  // xgL visible to all waves

    // ---- REC phase: steps tc .. tstop, xg from LDS with 1-step prefetch ----
    half8 cur = *(const half8*)&xgL[0][u * 8];
    for (int t = tc; t <= tstop; ++t) {
      int nidx = min(t + 1 - tc, CH - 1);  // clamped; stale at chunk end (unused)
      half8 nxt = *(const half8*)&xgL[nidx][u * 8];
      if ((t & 1) == 0) STEP(t, cur, 0, 1);
      else              STEP(t, cur, 1, 0);
      cur = nxt;
    }
  }
#undef STEP
}

extern "C" void kernel_launch(void* const* d_in, const int* in_sizes, int n_in,
                              void* d_out, int out_size, void* d_ws, size_t ws_size,
                              hipStream_t stream) {
  const float* x = (const float*)d_in[0];
  const float* dur = (const float*)d_in[1];
  const int* rep = (const int*)d_in[2];
  const float* Wx = (const float*)d_in[3];
  const float* Wh = (const float*)d_in[4];
  const float* bias = (const float*)d_in[5];
  float* out = (float*)d_out;
  char* ws = (char*)d_ws;

  size_t off = 0;
  _Float16* WxT = (_Float16*)(ws + off); off += (size_t)NG * DD * 2;
  _Float16* WhT = (_Float16*)(ws + off); off += (size_t)NG * DD * 2;

  hipLaunchKernelGGL(wtrans_k, dim3((2 * DD * NG + 255) / 256), dim3(256), 0, stream,
                     Wx, Wh, WxT, WhT);
  hipLaunchKernelGGL(rec_k, dim3(BB), dim3(512), 0, stream,
                     x, dur, rep, WxT, WhT, bias, out);
}

// Round 12
// 182.524 us; speedup vs baseline: 2.2441x; 1.4480x over previous
//
#include <hip/hip_runtime.h>

#define TT 200
#define BB 256
#define DD 128
#define HH 128
#define NG 896    // 7*H semantic gate dim (gate-major: col = g*128 + u)
#define NGP 1024  // padded xg: pcol = u*8 + gate, gate 7 = zero pad

typedef _Float16 half8 __attribute__((ext_vector_type(8)));
typedef _Float16 half4 __attribute__((ext_vector_type(4)));
typedef float float4v __attribute__((ext_vector_type(4)));
typedef int int4v __attribute__((ext_vector_type(4)));

__device__ __forceinline__ float rcpf_(float x) { return __builtin_amdgcn_rcpf(x); }
__device__ __forceinline__ float sigmoidf_(float x) { return rcpf_(1.f + __expf(-x)); }
__device__ __forceinline__ float tanhf_(float x) { return 1.f - 2.f * rcpf_(__expf(2.f * x) + 1.f); }
// softplus(x) = max(x,0) + ln(1+exp(-|x|))
__device__ __forceinline__ float softplusf_(float x) {
  return fmaxf(x, 0.f) + 0.69314718056f * __log2f(1.f + __expf(-fabsf(x)));
}

// Weight prep for xg path: WxTp[pcol][k] (pcol=u*8+g, padded), bias_p[pcol]
__global__ __launch_bounds__(256) void wtrans_k(const float* __restrict__ Wx,
    const float* __restrict__ bias, _Float16* __restrict__ WxTp, float* __restrict__ bias_p) {
  int idx = blockIdx.x * 256 + threadIdx.x;
  if (idx < NGP * DD) {  // WxTp
    int pcol = idx >> 7, k = idx & 127;
    int u = pcol >> 3, g = pcol & 7;
    WxTp[idx] = (g < 7) ? (_Float16)Wx[k * NG + g * HH + u] : (_Float16)0.f;
  } else if (idx < NGP * DD + NGP) {  // bias_p
    int pcol = idx - NGP * DD;
    int u = pcol >> 3, g = pcol & 7;
    bias_p[pcol] = (g < 7) ? bias[g * HH + u] : 0.f;
  }
}

// W_h int8 quantization, per-column scale: WhQ[col][k] i8, wscale[col] f32.
// col is semantic (g*128+u). Reads of Wh[k*NG+col] are coalesced over threads.
__global__ __launch_bounds__(256) void wquant_k(const float* __restrict__ Wh,
    char* __restrict__ WhQ, float* __restrict__ wscale) {
  int col = blockIdx.x * 256 + threadIdx.x;
  if (col >= NG) return;
  float m = 0.f;
  for (int k = 0; k < DD; ++k) m = fmaxf(m, fabsf(Wh[k * NG + col]));
  float mm = m > 0.f ? m : 1.f;
  float inv = 127.f * rcpf_(mm);
  for (int k = 0; k < DD; ++k)
    WhQ[col * DD + k] = (char)__float2int_rn(Wh[k * NG + col] * inv);
  wscale[col] = mm * (1.f / 127.f);
}

// xg GEMM (unchanged r9 champion): A-tile staged once per block, nt-loop inside.
__global__ __launch_bounds__(256, 2) void xg_gemm_k(const float* __restrict__ x,
    const _Float16* __restrict__ WxTp, const float* __restrict__ bias_p,
    _Float16* __restrict__ xg, int t0) {
  int mt = blockIdx.x;
  __shared__ _Float16 Ald[128][136];
  __shared__ _Float16 Bld[128][136];
  int tid = threadIdx.x;
  int G0 = mt * 128;
  int t = t0 + (G0 >> 8);
  int b0 = G0 & 255;
  {
    int r = tid >> 5, kq = (tid & 31) << 2;
#pragma unroll
    for (int it = 0; it < 16; ++it) {
      int row = r + it * 8;
      float4v xv = *(const float4v*)(x + ((size_t)(b0 + row) * TT + t) * DD + kq);
      half4 h4 = {(_Float16)xv[0], (_Float16)xv[1], (_Float16)xv[2], (_Float16)xv[3]};
      *(half4*)&Ald[row][kq] = h4;
    }
  }
  __syncthreads();
  int wv = tid >> 6, l = tid & 63, lr = l & 15, lk8 = (l >> 4) << 3;
  half8 af[2][4];
#pragma unroll
  for (int mf = 0; mf < 2; ++mf)
#pragma unroll
    for (int kk = 0; kk < 4; ++kk)
      af[mf][kk] = *(const half8*)&Ald[wv * 32 + mf * 16 + lr][kk * 32 + lk8];

  for (int nt = 0; nt < 8; ++nt) {
    for (int i = tid; i < 128 * 16; i += 256) {
      int r = i >> 4, c8 = (i & 15) << 3;
      *(half8*)&Bld[r][c8] = *(const half8*)(WxTp + (size_t)(nt * 128 + r) * DD + c8);
    }
    __syncthreads();
    float4v acc[2][8];
#pragma unroll
    for (int a = 0; a < 2; ++a)
#pragma unroll
      for (int q = 0; q < 8; ++q) acc[a][q] = (float4v){0.f, 0.f, 0.f, 0.f};
#pragma unroll
    for (int kk = 0; kk < 4; ++kk) {
#pragma unroll
      for (int nf = 0; nf < 8; ++nf) {
        half8 bv = *(const half8*)&Bld[nf * 16 + lr][kk * 32 + lk8];
        acc[0][nf] = __builtin_amdgcn_mfma_f32_16x16x32_f16(af[0][kk], bv, acc[0][nf], 0, 0, 0);
        acc[1][nf] = __builtin_amdgcn_mfma_f32_16x16x32_f16(af[1][kk], bv, acc[1][nf], 0, 0, 0);
      }
    }
    int r4 = (l >> 4) << 2;
#pragma unroll
    for (int nf = 0; nf < 8; ++nf) {
      int col = nt * 128 + nf * 16 + lr;
      float bv = bias_p[col];
#pragma unroll
      for (int mf = 0; mf < 2; ++mf) {
        int row = G0 + wv * 32 + mf * 16 + r4;
#pragma unroll
        for (int rr = 0; rr < 4; ++rr) {
          xg[(size_t)(row + rr) * NGP + col] = (_Float16)(acc[mf][nf][rr] + bv);
        }
      }
    }
    __syncthreads();
  }
}

// MFMA recurrence, i8 weights+h: r9 structure (1 block/sample, 512 threads,
// one __syncthreads per step, 8-batch xg prefetch), but h@W_h uses
// mfma_i32_16x16x64_i8: K=128 in TWO MFMAs per gate (14/wave/step vs 28) at
// 2x rate -> MFMA pipe time per SIMD/step halves (~1150 -> ~570 cy).
// W_h quantized per-column (wscale); h quantized to i8 at scale 127 (|h|<1
// strictly since h = sigmoid*tanh). Accumulation exact i32; dequant 1 fma/gate.
__global__ __launch_bounds__(512, 2) void rec_k(const _Float16* __restrict__ xg,
    const float* __restrict__ dur, const int* __restrict__ rep,
    const char* __restrict__ WhQ, const float* __restrict__ wscale,
    float* __restrict__ out,
    char* __restrict__ st_h, float* __restrict__ st_c, float* __restrict__ st_cb,
    int t0, int t1) {
  int b = blockIdx.x, j = threadIdx.x;
  int tend = rep[b];
  if (t0 > tend) return;  // block-uniform
  int tstop = min(t1 - 1, tend);
  __shared__ __align__(16) char hq[2][HH];  // i8 h, double-buffered
  __shared__ float dlds[TT];
  int w = j >> 6, l = j & 63, lr = l & 15, lg = l >> 4;
  int u = w * 16 + lr;

  // B-fragments: wbq[g][m] = WhQ[col=g*128+u][k = m*64 + lg*16 .. +16] (16 i8)
  int4v wbq[7][2];
#pragma unroll
  for (int g = 0; g < 7; ++g)
#pragma unroll
    for (int m = 0; m < 2; ++m)
      wbq[g][m] = *(const int4v*)(WhQ + (size_t)(g * HH + u) * DD + m * 64 + lg * 16);
  float sg[7];
#pragma unroll
  for (int g = 0; g < 7; ++g) sg[g] = wscale[g * HH + u] * (1.f / 127.f);
  for (int i = j; i < TT; i += 512) dlds[i] = dur[b * TT + i];
  float c_s = 0.f, cb_s = 0.f;
  if (lg == 0) {
    hq[0][u] = (t0 == 0) ? (char)0 : st_h[b * HH + u];
    hq[1][u] = (char)0;
  }
  if (t0 != 0) {
    c_s = st_c[b * HH + u];
    cb_s = st_cb[b * HH + u];
  }
  __syncthreads();

  const _Float16* xgp = xg + (size_t)b * NGP + u * 8;  // + step*stp, aligned 16B
  const size_t stp = (size_t)BB * NGP;
  half8 cur[8], nxt[8];
#pragma unroll
  for (int i = 0; i < 8; ++i)
    cur[i] = *(const half8*)(xgp + (size_t)(min(t0 + i, tstop) - t0) * stp);
  float hsave = 0.f;
  char hqsave = 0;

#define STEP(T, CUR, PIN, POUT)                                                  \
  do {                                                                           \
    float dt = dlds[T];                                                          \
    int4v aq0 = *(const int4v*)&hq[PIN][lg * 16];                                \
    int4v aq1 = *(const int4v*)&hq[PIN][64 + lg * 16];                           \
    int4v acc[7];                                                                \
    _Pragma("unroll") for (int g = 0; g < 7; ++g) acc[g] = (int4v){0, 0, 0, 0};  \
    _Pragma("unroll") for (int g = 0; g < 7; ++g)                                \
        acc[g] = __builtin_amdgcn_mfma_i32_16x16x64_i8(aq0, wbq[g][0], acc[g], 0, 0, 0); \
    _Pragma("unroll") for (int g = 0; g < 7; ++g)                                \
        acc[g] = __builtin_amdgcn_mfma_i32_16x16x64_i8(aq1, wbq[g][1], acc[g], 0, 0, 0); \
    float gv[7];                                                                 \
    _Pragma("unroll") for (int g = 0; g < 7; ++g)                                \
        gv[g] = (float)acc[g][0] * sg[g] + (float)CUR[g];                        \
    float iv = sigmoidf_(gv[0]), fv = sigmoidf_(gv[1]);                          \
    float zv = tanhf_(gv[2]), ov = sigmoidf_(gv[3]);                             \
    float ibv = sigmoidf_(gv[4]), fbv = sigmoidf_(gv[5]);                        \
    float dv = softplusf_(gv[6]);                                                \
    float cc = fv * c_s + iv * zv;                                               \
    cb_s = fbv * cb_s + ibv * zv;                                                \
    float cn = cb_s + (cc - cb_s) * __expf(-dv * dt);                            \
    float hn = ov * tanhf_(cn);                                                  \
    c_s = cn;                                                                    \
    hsave = hn;                                                                  \
    char hb = (char)__float2int_rn(hn * 127.f);                                  \
    hqsave = hb;                                                                 \
    if (lg == 0) {                                                               \
      if ((T) == tend) {                                                         \
        out[b * HH + u] = hn;                                                    \
        out[BB * HH + b * HH + u] = cn;                                          \
      }                                                                          \
      hq[POUT][u] = hb;                                                          \
    }                                                                            \
    __syncthreads();                                                             \
  } while (0)

  for (int tb = t0; tb <= tstop; tb += 8) {
    // issue next batch's 8 loads up front; they complete well before the
    // first STEP barrier's vmcnt drain (~1 full step of slack)
#pragma unroll
    for (int i = 0; i < 8; ++i)
      nxt[i] = *(const half8*)(xgp + (size_t)(min(tb + 8 + i, tstop) - t0) * stp);
    STEP(tb, cur[0], 0, 1);
    if (tb + 1 <= tstop) STEP(tb + 1, cur[1], 1, 0);
    if (tb + 2 <= tstop) STEP(tb + 2, cur[2], 0, 1);
    if (tb + 3 <= tstop) STEP(tb + 3, cur[3], 1, 0);
    if (tb + 4 <= tstop) STEP(tb + 4, cur[4], 0, 1);
    if (tb + 5 <= tstop) STEP(tb + 5, cur[5], 1, 0);
    if (tb + 6 <= tstop) STEP(tb + 6, cur[6], 0, 1);
    if (tb + 7 <= tstop) STEP(tb + 7, cur[7], 1, 0);
#pragma unroll
    for (int i = 0; i < 8; ++i) cur[i] = nxt[i];
  }
#undef STEP

  if (tstop < tend && lg == 0) {  // save state for next chunk (h as exact i8)
    st_h[b * HH + u] = hqsave;
    st_c[b * HH + u] = c_s;
    st_cb[b * HH + u] = cb_s;
  }
  (void)hsave;
}

extern "C" void kernel_launch(void* const* d_in, const int* in_sizes, int n_in,
                              void* d_out, int out_size, void* d_ws, size_t ws_size,
                              hipStream_t stream) {
  const float* x = (const float*)d_in[0];
  const float* dur = (const float*)d_in[1];
  const int* rep = (const int*)d_in[2];
  const float* Wx = (const float*)d_in[3];
  const float* Wh = (const float*)d_in[4];
  const float* bias = (const float*)d_in[5];
  float* out = (float*)d_out;
  char* ws = (char*)d_ws;

  size_t off = 0;
  _Float16* WxTp = (_Float16*)(ws + off); off += (size_t)NGP * DD * 2;
  float* bias_p = (float*)(ws + off); off += (size_t)NGP * 4;
  char* WhQ = (char*)(ws + off); off += (size_t)NG * DD;
  float* wscale = (float*)(ws + off); off += (size_t)NG * 4;
  char* st_h = (char*)(ws + off); off += (size_t)BB * HH;
  float* st_c = (float*)(ws + off); off += (size_t)BB * HH * 4;
  float* st_cb = (float*)(ws + off); off += (size_t)BB * HH * 4;
  off = (off + 255) & ~(size_t)255;
  _Float16* xgbuf = (_Float16*)(ws + off);

  size_t avail = ws_size > off ? ws_size - off : 0;
  size_t perT = (size_t)BB * NGP * 2;
  int Tc = (int)(avail / perT);
  if (Tc > TT) Tc = TT;
  if (Tc < 1) Tc = 1;

  int nprep = NGP * DD + NGP;
  hipLaunchKernelGGL(wtrans_k, dim3((nprep + 255) / 256), dim3(256), 0, stream,
                     Wx, bias, WxTp, bias_p);
  hipLaunchKernelGGL(wquant_k, dim3((NG + 255) / 256), dim3(256), 0, stream,
                     Wh, WhQ, wscale);
  for (int t0 = 0; t0 < TT; t0 += Tc) {
    int t1 = t0 + Tc;
    if (t1 > TT) t1 = TT;
    int mtiles = (t1 - t0) * BB / 128;
    hipLaunchKernelGGL(xg_gemm_k, dim3(mtiles), dim3(256), 0, stream,
                       x, WxTp, bias_p, xgbuf, t0);
    hipLaunchKernelGGL(rec_k, dim3(BB), dim3(512), 0, stream,
                       xgbuf, dur, rep, WhQ, wscale, out, st_h, st_c, st_cb, t0, t1);
  }
}